// Round 1
// baseline (2079.615 us; speedup 1.0000x reference)
//
#include <hip/hip_runtime.h>
#include <cmath>

#define T_SEQ 1024
#define EMB   1024
#define NH    16
#define HD    64
#define NB    4

// ---------------------------------------------------------------------------
// GEMM: out = A(M x K) @ W(N x K)^T + bias
// BM=BN=128, BK=16, 256 threads, 8x8 micro-tile per thread.
// LDS tiles stored k-major (transposed) so compute reads are float4.
// splitHeads: write out as (B, H, T, D) scatter instead of (M, N).
// ---------------------------------------------------------------------------
__global__ __launch_bounds__(256) void gemm_bias(
    const float* __restrict__ A, const float* __restrict__ W,
    const float* __restrict__ bias, float* __restrict__ out,
    int M, int N, int K, int splitHeads)
{
    __shared__ float As[16][132];
    __shared__ float Bs[16][132];

    const int tid = threadIdx.x;
    const int m0 = blockIdx.y * 128;
    const int n0 = blockIdx.x * 128;
    const int tr = tid >> 4;   // 0..15 (row group of 8)
    const int tc = tid & 15;   // 0..15 (col group of 8)

    float acc[8][8];
#pragma unroll
    for (int i = 0; i < 8; ++i)
#pragma unroll
        for (int j = 0; j < 8; ++j) acc[i][j] = 0.0f;

    for (int kk = 0; kk < K; kk += 16) {
        __syncthreads();
        // Stage A tile (128 x 16) transposed into As[k][m]
        {
            int f = tid;                 // first half
            int m = f >> 2, k4 = f & 3;
            float4 va = *(const float4*)&A[(size_t)(m0 + m) * K + kk + k4 * 4];
            As[k4 * 4 + 0][m] = va.x; As[k4 * 4 + 1][m] = va.y;
            As[k4 * 4 + 2][m] = va.z; As[k4 * 4 + 3][m] = va.w;
            f = tid + 256;               // second half
            m = f >> 2; k4 = f & 3;
            va = *(const float4*)&A[(size_t)(m0 + m) * K + kk + k4 * 4];
            As[k4 * 4 + 0][m] = va.x; As[k4 * 4 + 1][m] = va.y;
            As[k4 * 4 + 2][m] = va.z; As[k4 * 4 + 3][m] = va.w;
        }
        // Stage W tile (128 x 16) transposed into Bs[k][n]
        {
            int f = tid;
            int n = f >> 2, k4 = f & 3;
            float4 vb = *(const float4*)&W[(size_t)(n0 + n) * K + kk + k4 * 4];
            Bs[k4 * 4 + 0][n] = vb.x; Bs[k4 * 4 + 1][n] = vb.y;
            Bs[k4 * 4 + 2][n] = vb.z; Bs[k4 * 4 + 3][n] = vb.w;
            f = tid + 256;
            n = f >> 2; k4 = f & 3;
            vb = *(const float4*)&W[(size_t)(n0 + n) * K + kk + k4 * 4];
            Bs[k4 * 4 + 0][n] = vb.x; Bs[k4 * 4 + 1][n] = vb.y;
            Bs[k4 * 4 + 2][n] = vb.z; Bs[k4 * 4 + 3][n] = vb.w;
        }
        __syncthreads();

#pragma unroll
        for (int k = 0; k < 16; ++k) {
            float a[8], b[8];
            *(float4*)&a[0] = *(const float4*)&As[k][tr * 8];
            *(float4*)&a[4] = *(const float4*)&As[k][tr * 8 + 4];
            *(float4*)&b[0] = *(const float4*)&Bs[k][tc * 8];
            *(float4*)&b[4] = *(const float4*)&Bs[k][tc * 8 + 4];
#pragma unroll
            for (int i = 0; i < 8; ++i)
#pragma unroll
                for (int j = 0; j < 8; ++j)
                    acc[i][j] += a[i] * b[j];
        }
    }

    // Epilogue
#pragma unroll
    for (int i = 0; i < 8; ++i) {
        const int m = m0 + tr * 8 + i;
        const int bb = m >> 10;          // batch (T=1024)
        const int t  = m & 1023;
#pragma unroll
        for (int j4 = 0; j4 < 2; ++j4) {
            const int n = n0 + tc * 8 + j4 * 4;
            float4 r;
            r.x = acc[i][j4 * 4 + 0] + bias[n + 0];
            r.y = acc[i][j4 * 4 + 1] + bias[n + 1];
            r.z = acc[i][j4 * 4 + 2] + bias[n + 2];
            r.w = acc[i][j4 * 4 + 3] + bias[n + 3];
            if (splitHeads) {
                const int h = n >> 6, d = n & 63;
                *(float4*)&out[(((size_t)bb * NH + h) * T_SEQ + t) * HD + d] = r;
            } else {
                *(float4*)&out[(size_t)m * N + n] = r;
            }
        }
    }
}

// ---------------------------------------------------------------------------
// Flash-style attention, fp32. One thread per q row, KV tiles of 32 in LDS.
// q,k,v laid out (B, H, T, D). Output written (B, T, E).
// grid (T/256, NH, NB), block 256.
// ---------------------------------------------------------------------------
__global__ __launch_bounds__(256) void flash_attn(
    const float* __restrict__ q, const float* __restrict__ k,
    const float* __restrict__ v, const int* __restrict__ mask,
    float* __restrict__ out)
{
    __shared__ float Ks[32][64];
    __shared__ float Vs[32][64];

    const int tid = threadIdx.x;
    const int b = blockIdx.z;
    const int h = blockIdx.y;
    const int qrow = blockIdx.x * 256 + tid;

    // load q row into registers (16 float4)
    float4 qr[16];
    const float4* qp = (const float4*)&q[(((size_t)b * NH + h) * T_SEQ + qrow) * HD];
#pragma unroll
    for (int i = 0; i < 16; ++i) qr[i] = qp[i];

    float4 o[16];
#pragma unroll
    for (int i = 0; i < 16; ++i) o[i] = make_float4(0.f, 0.f, 0.f, 0.f);

    float mrun = -INFINITY;
    float lrun = 0.0f;

    const int4* mrow4 = (const int4*)&mask[((size_t)b * T_SEQ + qrow) * T_SEQ];
    const float* kbase = &k[(((size_t)b * NH + h) * T_SEQ) * HD];
    const float* vbase = &v[(((size_t)b * NH + h) * T_SEQ) * HD];

    for (int kt = 0; kt < T_SEQ / 32; ++kt) {
        __syncthreads();
        // stage K, V tiles (32 x 64 each): 512 float4 each, 2 per thread
        {
            int f = tid;
            int r = f >> 4, c4 = f & 15;
            *(float4*)&Ks[r][c4 * 4] =
                *(const float4*)&kbase[(size_t)(kt * 32 + r) * HD + c4 * 4];
            *(float4*)&Vs[r][c4 * 4] =
                *(const float4*)&vbase[(size_t)(kt * 32 + r) * HD + c4 * 4];
            f = tid + 256;
            r = f >> 4; c4 = f & 15;
            *(float4*)&Ks[r][c4 * 4] =
                *(const float4*)&kbase[(size_t)(kt * 32 + r) * HD + c4 * 4];
            *(float4*)&Vs[r][c4 * 4] =
                *(const float4*)&vbase[(size_t)(kt * 32 + r) * HD + c4 * 4];
        }
        __syncthreads();

        float s[32];
        float tmax = -INFINITY;
#pragma unroll
        for (int j4 = 0; j4 < 8; ++j4) {
            const int4 mm = mrow4[kt * 8 + j4];
            const int mv[4] = { mm.x, mm.y, mm.z, mm.w };
#pragma unroll
            for (int u = 0; u < 4; ++u) {
                const int j = j4 * 4 + u;
                const float4* kr = (const float4*)&Ks[j][0];
                float d0 = 0.f, d1 = 0.f;
#pragma unroll
                for (int i = 0; i < 16; i += 2) {
                    d0 += qr[i].x * kr[i].x + qr[i].y * kr[i].y +
                          qr[i].z * kr[i].z + qr[i].w * kr[i].w;
                    d1 += qr[i+1].x * kr[i+1].x + qr[i+1].y * kr[i+1].y +
                          qr[i+1].z * kr[i+1].z + qr[i+1].w * kr[i+1].w;
                }
                const float sc = (d0 + d1) * 0.125f;    // / sqrt(64)
                s[j] = mv[u] ? sc : -1.0e9f;
                tmax = fmaxf(tmax, s[j]);
            }
        }

        const float mnew = fmaxf(mrun, tmax);
        const float corr = __expf(mrun - mnew);   // exp(-inf)=0 on first tile
        lrun *= corr;
#pragma unroll
        for (int i = 0; i < 16; ++i) {
            o[i].x *= corr; o[i].y *= corr; o[i].z *= corr; o[i].w *= corr;
        }
#pragma unroll
        for (int j = 0; j < 32; ++j) {
            const float p = __expf(s[j] - mnew);
            lrun += p;
            const float4* vr = (const float4*)&Vs[j][0];
#pragma unroll
            for (int i = 0; i < 16; ++i) {
                o[i].x += p * vr[i].x; o[i].y += p * vr[i].y;
                o[i].z += p * vr[i].z; o[i].w += p * vr[i].w;
            }
        }
        mrun = mnew;
    }

    const float inv = 1.0f / lrun;
    float4* op = (float4*)&out[((size_t)b * T_SEQ + qrow) * EMB + h * HD];
#pragma unroll
    for (int i = 0; i < 16; ++i) {
        float4 r;
        r.x = o[i].x * inv; r.y = o[i].y * inv;
        r.z = o[i].z * inv; r.w = o[i].w * inv;
        op[i] = r;
    }
}

// ---------------------------------------------------------------------------
// LayerNorm over last dim (1024). One block (256 thr) per row.
// ---------------------------------------------------------------------------
__global__ __launch_bounds__(256) void layernorm_k(
    const float* __restrict__ x, const float* __restrict__ gamma,
    const float* __restrict__ beta, float* __restrict__ out)
{
    __shared__ float ws1[4], ws2[4];
    const int tid = threadIdx.x;
    const size_t row = blockIdx.x;

    const float4 v = *(const float4*)&x[row * EMB + tid * 4];
    float s  = v.x + v.y + v.z + v.w;
    float ss = v.x * v.x + v.y * v.y + v.z * v.z + v.w * v.w;
#pragma unroll
    for (int off = 32; off > 0; off >>= 1) {
        s  += __shfl_down(s, off);
        ss += __shfl_down(ss, off);
    }
    if ((tid & 63) == 0) { ws1[tid >> 6] = s; ws2[tid >> 6] = ss; }
    __syncthreads();
    if (tid == 0) {
        const float a = ws1[0] + ws1[1] + ws1[2] + ws1[3];
        const float bsum = ws2[0] + ws2[1] + ws2[2] + ws2[3];
        const float mu = a * (1.0f / EMB);
        const float var = bsum * (1.0f / EMB) - mu * mu;
        ws1[0] = mu;
        ws2[0] = rsqrtf(var + 1e-5f);
    }
    __syncthreads();
    const float mu = ws1[0], rstd = ws2[0];

    const float4 g = *(const float4*)&gamma[tid * 4];
    const float4 bt = *(const float4*)&beta[tid * 4];
    float4 r;
    r.x = (v.x - mu) * rstd * g.x + bt.x;
    r.y = (v.y - mu) * rstd * g.y + bt.y;
    r.z = (v.z - mu) * rstd * g.z + bt.z;
    r.w = (v.w - mu) * rstd * g.w + bt.w;
    *(float4*)&out[row * EMB + tid * 4] = r;
}

// ---------------------------------------------------------------------------
extern "C" void kernel_launch(void* const* d_in, const int* in_sizes, int n_in,
                              void* d_out, int out_size, void* d_ws, size_t ws_size,
                              hipStream_t stream) {
    const float* query = (const float*)d_in[0];
    const float* key_i = (const float*)d_in[1];
    const float* value = (const float*)d_in[2];
    const int*   mask  = (const int*)d_in[3];
    const float* Wq = (const float*)d_in[4];
    const float* bq = (const float*)d_in[5];
    const float* Wk = (const float*)d_in[6];
    const float* bk = (const float*)d_in[7];
    const float* Wv = (const float*)d_in[8];
    const float* bv = (const float*)d_in[9];
    const float* Wo = (const float*)d_in[10];
    const float* bo = (const float*)d_in[11];
    const float* gamma = (const float*)d_in[12];
    const float* beta  = (const float*)d_in[13];

    float* ws = (float*)d_ws;
    const size_t SZ = (size_t)NB * T_SEQ * EMB;   // 4,194,304 floats
    float* qb    = ws;
    float* kb    = ws + SZ;
    float* vb    = ws + 2 * SZ;
    float* attnb = ws + 3 * SZ;
    float* projb = qb;   // q dead after attention; reuse

    const int M = NB * T_SEQ;   // 4096
    dim3 gg(EMB / 128, M / 128);  // (8, 32)
    dim3 blk(256);

    gemm_bias<<<gg, blk, 0, stream>>>(query, Wq, bq, qb, M, EMB, EMB, 1);
    gemm_bias<<<gg, blk, 0, stream>>>(key_i, Wk, bk, kb, M, EMB, EMB, 1);
    gemm_bias<<<gg, blk, 0, stream>>>(value, Wv, bv, vb, M, EMB, EMB, 1);

    flash_attn<<<dim3(T_SEQ / 256, NH, NB), blk, 0, stream>>>(qb, kb, vb, mask, attnb);

    gemm_bias<<<gg, blk, 0, stream>>>(attnb, Wo, bo, projb, M, EMB, EMB, 0);

    layernorm_k<<<dim3(M), blk, 0, stream>>>(projb, gamma, beta, (float*)d_out);
}

// Round 2
// 1052.950 us; speedup vs baseline: 1.9750x; 1.9750x over previous
//
#include <hip/hip_runtime.h>
#include <cmath>

#define T_SEQ 1024
#define EMB   1024
#define NH    16
#define HD    64
#define NB    4
#define BQ    64
#define BK    64

using frag8  = __attribute__((ext_vector_type(8))) short;
using f32x4  = __attribute__((ext_vector_type(4))) float;
using short4v = __attribute__((ext_vector_type(4))) short;
using short8v = __attribute__((ext_vector_type(8))) short;

__device__ inline short f2bf(float f) {
    union { float f; unsigned u; } x; x.f = f;
    unsigned r = (x.u + 0x7FFFu + ((x.u >> 16) & 1u)) >> 16;
    return (short)r;
}

// ---------------------------------------------------------------------------
// GEMM: out = A(M x K) @ W(N x K)^T + bias   (fp32, unchanged from round 1)
// ---------------------------------------------------------------------------
__global__ __launch_bounds__(256) void gemm_bias(
    const float* __restrict__ A, const float* __restrict__ W,
    const float* __restrict__ bias, float* __restrict__ out,
    int M, int N, int K, int splitHeads)
{
    __shared__ float As[16][132];
    __shared__ float Bs[16][132];

    const int tid = threadIdx.x;
    const int m0 = blockIdx.y * 128;
    const int n0 = blockIdx.x * 128;
    const int tr = tid >> 4;
    const int tc = tid & 15;

    float acc[8][8];
#pragma unroll
    for (int i = 0; i < 8; ++i)
#pragma unroll
        for (int j = 0; j < 8; ++j) acc[i][j] = 0.0f;

    for (int kk = 0; kk < K; kk += 16) {
        __syncthreads();
        {
            int f = tid;
            int m = f >> 2, k4 = f & 3;
            float4 va = *(const float4*)&A[(size_t)(m0 + m) * K + kk + k4 * 4];
            As[k4 * 4 + 0][m] = va.x; As[k4 * 4 + 1][m] = va.y;
            As[k4 * 4 + 2][m] = va.z; As[k4 * 4 + 3][m] = va.w;
            f = tid + 256;
            m = f >> 2; k4 = f & 3;
            va = *(const float4*)&A[(size_t)(m0 + m) * K + kk + k4 * 4];
            As[k4 * 4 + 0][m] = va.x; As[k4 * 4 + 1][m] = va.y;
            As[k4 * 4 + 2][m] = va.z; As[k4 * 4 + 3][m] = va.w;
        }
        {
            int f = tid;
            int n = f >> 2, k4 = f & 3;
            float4 vb = *(const float4*)&W[(size_t)(n0 + n) * K + kk + k4 * 4];
            Bs[k4 * 4 + 0][n] = vb.x; Bs[k4 * 4 + 1][n] = vb.y;
            Bs[k4 * 4 + 2][n] = vb.z; Bs[k4 * 4 + 3][n] = vb.w;
            f = tid + 256;
            n = f >> 2; k4 = f & 3;
            vb = *(const float4*)&W[(size_t)(n0 + n) * K + kk + k4 * 4];
            Bs[k4 * 4 + 0][n] = vb.x; Bs[k4 * 4 + 1][n] = vb.y;
            Bs[k4 * 4 + 2][n] = vb.z; Bs[k4 * 4 + 3][n] = vb.w;
        }
        __syncthreads();

#pragma unroll
        for (int k = 0; k < 16; ++k) {
            float a[8], b[8];
            *(float4*)&a[0] = *(const float4*)&As[k][tr * 8];
            *(float4*)&a[4] = *(const float4*)&As[k][tr * 8 + 4];
            *(float4*)&b[0] = *(const float4*)&Bs[k][tc * 8];
            *(float4*)&b[4] = *(const float4*)&Bs[k][tc * 8 + 4];
#pragma unroll
            for (int i = 0; i < 8; ++i)
#pragma unroll
                for (int j = 0; j < 8; ++j)
                    acc[i][j] += a[i] * b[j];
        }
    }

#pragma unroll
    for (int i = 0; i < 8; ++i) {
        const int m = m0 + tr * 8 + i;
        const int bb = m >> 10;
        const int t  = m & 1023;
#pragma unroll
        for (int j4 = 0; j4 < 2; ++j4) {
            const int n = n0 + tc * 8 + j4 * 4;
            float4 r;
            r.x = acc[i][j4 * 4 + 0] + bias[n + 0];
            r.y = acc[i][j4 * 4 + 1] + bias[n + 1];
            r.z = acc[i][j4 * 4 + 2] + bias[n + 2];
            r.w = acc[i][j4 * 4 + 3] + bias[n + 3];
            if (splitHeads) {
                const int h = n >> 6, d = n & 63;
                *(float4*)&out[(((size_t)bb * NH + h) * T_SEQ + t) * HD + d] = r;
            } else {
                *(float4*)&out[(size_t)m * N + n] = r;
            }
        }
    }
}

// ---------------------------------------------------------------------------
// MFMA bf16 flash attention. Block = 256 thr (4 waves). BQ=64 (16 q/wave),
// BK=64. q,k,v: (B,H,T,D) fp32. mask: (B,1,T,T) int. out: (B,T,E) fp32.
// grid (T/BQ, NH, NB).
// ---------------------------------------------------------------------------
__global__ __launch_bounds__(256) void flash_attn_mfma(
    const float* __restrict__ q, const float* __restrict__ k,
    const float* __restrict__ v, const int* __restrict__ mask,
    float* __restrict__ out)
{
    __shared__ short Ks[64][72];      // [key][d], pad 72 for bank-uniform b128
    __shared__ short Vt[64][64];      // [d][k ^ swz(d)]  (xor-swizzled)
    __shared__ short Mh[64][72];      // mask tile as 0/1 shorts
    __shared__ short Pl[4][16][72];   // per-wave P round-trip

    const int tid  = threadIdx.x;
    const int wave = tid >> 6;
    const int lane = tid & 63;
    const int quad = lane >> 4;
    const int lm   = lane & 15;

    const int b  = blockIdx.z, h = blockIdx.y;
    const int q0 = blockIdx.x * BQ;

    // Q fragments: A-layout m=lm (q row of this wave), k = quad*8+j (d)
    const float* qrow = q + (((size_t)b * NH + h) * T_SEQ + q0 + wave * 16 + lm) * HD;
    frag8 qf0, qf1;
#pragma unroll
    for (int j = 0; j < 8; ++j) {
        qf0[j] = f2bf(qrow[quad * 8 + j]);
        qf1[j] = f2bf(qrow[32 + quad * 8 + j]);
    }

    f32x4 of[4];
#pragma unroll
    for (int dc = 0; dc < 4; ++dc) of[dc] = (f32x4){0.f, 0.f, 0.f, 0.f};
    float mrun[4], lrun[4];
#pragma unroll
    for (int r = 0; r < 4; ++r) { mrun[r] = -INFINITY; lrun[r] = 0.f; }

    const float* kb0 = k + (((size_t)b * NH + h) * T_SEQ) * HD;
    const float* vb0 = v + (((size_t)b * NH + h) * T_SEQ) * HD;
    const int*   mb0 = mask + ((size_t)b * T_SEQ + q0) * T_SEQ;

    for (int kt = 0; kt < T_SEQ / BK; ++kt) {
        __syncthreads();
        // --- stage K tile (64 x 64) fp32 -> bf16, row-major ---
        {
            const int r = tid >> 2, sg = (tid & 3) * 16;
            const float* src = kb0 + (size_t)(kt * 64 + r) * HD + sg;
            short tmp[16];
#pragma unroll
            for (int u = 0; u < 4; ++u) {
                float4 fv = ((const float4*)src)[u];
                tmp[u * 4 + 0] = f2bf(fv.x); tmp[u * 4 + 1] = f2bf(fv.y);
                tmp[u * 4 + 2] = f2bf(fv.z); tmp[u * 4 + 3] = f2bf(fv.w);
            }
            *(short8v*)&Ks[r][sg]     = *(short8v*)&tmp[0];
            *(short8v*)&Ks[r][sg + 8] = *(short8v*)&tmp[8];
        }
        // --- stage mask tile as 0/1 shorts ---
        {
            const int r = tid >> 2, sg = (tid & 3) * 16;
            const int* src = mb0 + (size_t)r * T_SEQ + kt * 64 + sg;
            short tmp[16];
#pragma unroll
            for (int u = 0; u < 4; ++u) {
                int4 mi = ((const int4*)src)[u];
                tmp[u * 4 + 0] = (short)mi.x; tmp[u * 4 + 1] = (short)mi.y;
                tmp[u * 4 + 2] = (short)mi.z; tmp[u * 4 + 3] = (short)mi.w;
            }
            *(short8v*)&Mh[r][sg]     = *(short8v*)&tmp[0];
            *(short8v*)&Mh[r][sg + 8] = *(short8v*)&tmp[8];
        }
        // --- stage V transposed + xor-swizzled: Vt[d][k ^ ((d>>1)&7)<<3] ---
        {
            const int d0 = (tid & 15) * 4, k0 = (tid >> 4) * 4;
            float4 rv[4];
#pragma unroll
            for (int r = 0; r < 4; ++r)
                rv[r] = *(const float4*)(vb0 + (size_t)(kt * 64 + k0 + r) * HD + d0);
            const float rr0[4] = { rv[0].x, rv[0].y, rv[0].z, rv[0].w };
            const float rr1[4] = { rv[1].x, rv[1].y, rv[1].z, rv[1].w };
            const float rr2[4] = { rv[2].x, rv[2].y, rv[2].z, rv[2].w };
            const float rr3[4] = { rv[3].x, rv[3].y, rv[3].z, rv[3].w };
#pragma unroll
            for (int dd = 0; dd < 4; ++dd) {
                const int d = d0 + dd;
                short4v pk;
                pk[0] = f2bf(rr0[dd]); pk[1] = f2bf(rr1[dd]);
                pk[2] = f2bf(rr2[dd]); pk[3] = f2bf(rr3[dd]);
                const int col = k0 ^ (((d >> 1) & 7) << 3);
                *(short4v*)&Vt[d][col] = pk;
            }
        }
        __syncthreads();

        // --- S = Q K^T (C layout: col=lm=key, row=quad*4+r=q) ---
        f32x4 s[4];
#pragma unroll
        for (int kc = 0; kc < 4; ++kc) {
            frag8 kf0 = *(const frag8*)&Ks[kc * 16 + lm][quad * 8];
            frag8 kf1 = *(const frag8*)&Ks[kc * 16 + lm][32 + quad * 8];
            f32x4 acc = (f32x4){0.f, 0.f, 0.f, 0.f};
            acc = __builtin_amdgcn_mfma_f32_16x16x32_bf16(qf0, kf0, acc, 0, 0, 0);
            acc = __builtin_amdgcn_mfma_f32_16x16x32_bf16(qf1, kf1, acc, 0, 0, 0);
            s[kc] = acc;
        }

        // --- mask + scale + row max ---
        float tmax[4] = { -INFINITY, -INFINITY, -INFINITY, -INFINITY };
#pragma unroll
        for (int kc = 0; kc < 4; ++kc)
#pragma unroll
            for (int r = 0; r < 4; ++r) {
                float sv = s[kc][r] * 0.125f;
                sv = (Mh[wave * 16 + quad * 4 + r][kc * 16 + lm] != 0) ? sv : -1.0e9f;
                s[kc][r] = sv;
                tmax[r] = fmaxf(tmax[r], sv);
            }
#pragma unroll
        for (int r = 0; r < 4; ++r) {
            tmax[r] = fmaxf(tmax[r], __shfl_xor(tmax[r], 1));
            tmax[r] = fmaxf(tmax[r], __shfl_xor(tmax[r], 2));
            tmax[r] = fmaxf(tmax[r], __shfl_xor(tmax[r], 4));
            tmax[r] = fmaxf(tmax[r], __shfl_xor(tmax[r], 8));
        }

        // --- online softmax update ---
        float corr[4], rsum[4];
#pragma unroll
        for (int r = 0; r < 4; ++r) {
            const float mnew = fmaxf(mrun[r], tmax[r]);
            corr[r] = __expf(mrun[r] - mnew);
            mrun[r] = mnew;
            rsum[r] = 0.f;
        }
#pragma unroll
        for (int kc = 0; kc < 4; ++kc)
#pragma unroll
            for (int r = 0; r < 4; ++r) {
                const float p = __expf(s[kc][r] - mrun[r]);
                s[kc][r] = p;
                rsum[r] += p;
            }
#pragma unroll
        for (int r = 0; r < 4; ++r) {
            rsum[r] += __shfl_xor(rsum[r], 1);
            rsum[r] += __shfl_xor(rsum[r], 2);
            rsum[r] += __shfl_xor(rsum[r], 4);
            rsum[r] += __shfl_xor(rsum[r], 8);
            lrun[r] = lrun[r] * corr[r] + rsum[r];
        }
#pragma unroll
        for (int dc = 0; dc < 4; ++dc)
#pragma unroll
            for (int r = 0; r < 4; ++r) of[dc][r] *= corr[r];

        // --- P -> LDS (C layout -> A layout round trip) ---
#pragma unroll
        for (int kc = 0; kc < 4; ++kc)
#pragma unroll
            for (int r = 0; r < 4; ++r)
                Pl[wave][quad * 4 + r][kc * 16 + lm] = f2bf(s[kc][r]);

        // --- O += P V ---
        frag8 pf0 = *(const frag8*)&Pl[wave][lm][quad * 8];
        frag8 pf1 = *(const frag8*)&Pl[wave][lm][32 + quad * 8];
#pragma unroll
        for (int dc = 0; dc < 4; ++dc) {
            const int d = dc * 16 + lm;
            const int swz = ((d >> 1) & 7) << 3;
            frag8 vf0 = *(const frag8*)&Vt[d][(quad * 8) ^ swz];
            frag8 vf1 = *(const frag8*)&Vt[d][(32 + quad * 8) ^ swz];
            of[dc] = __builtin_amdgcn_mfma_f32_16x16x32_bf16(pf0, vf0, of[dc], 0, 0, 0);
            of[dc] = __builtin_amdgcn_mfma_f32_16x16x32_bf16(pf1, vf1, of[dc], 0, 0, 0);
        }
    }

    // --- epilogue: O / l, write (B,T,E) ---
    float inv[4];
#pragma unroll
    for (int r = 0; r < 4; ++r) inv[r] = 1.0f / lrun[r];
    float* ob = out + ((size_t)b * T_SEQ + q0 + wave * 16) * EMB + h * HD;
#pragma unroll
    for (int dc = 0; dc < 4; ++dc)
#pragma unroll
        for (int r = 0; r < 4; ++r)
            ob[(size_t)(quad * 4 + r) * EMB + dc * 16 + lm] = of[dc][r] * inv[r];
}

// ---------------------------------------------------------------------------
// LayerNorm over last dim (1024). One block (256 thr) per row.
// ---------------------------------------------------------------------------
__global__ __launch_bounds__(256) void layernorm_k(
    const float* __restrict__ x, const float* __restrict__ gamma,
    const float* __restrict__ beta, float* __restrict__ out)
{
    __shared__ float ws1[4], ws2[4];
    const int tid = threadIdx.x;
    const size_t row = blockIdx.x;

    const float4 v = *(const float4*)&x[row * EMB + tid * 4];
    float s  = v.x + v.y + v.z + v.w;
    float ss = v.x * v.x + v.y * v.y + v.z * v.z + v.w * v.w;
#pragma unroll
    for (int off = 32; off > 0; off >>= 1) {
        s  += __shfl_down(s, off);
        ss += __shfl_down(ss, off);
    }
    if ((tid & 63) == 0) { ws1[tid >> 6] = s; ws2[tid >> 6] = ss; }
    __syncthreads();
    if (tid == 0) {
        const float a = ws1[0] + ws1[1] + ws1[2] + ws1[3];
        const float bsum = ws2[0] + ws2[1] + ws2[2] + ws2[3];
        const float mu = a * (1.0f / EMB);
        const float var = bsum * (1.0f / EMB) - mu * mu;
        ws1[0] = mu;
        ws2[0] = rsqrtf(var + 1e-5f);
    }
    __syncthreads();
    const float mu = ws1[0], rstd = ws2[0];

    const float4 g = *(const float4*)&gamma[tid * 4];
    const float4 bt = *(const float4*)&beta[tid * 4];
    float4 r;
    r.x = (v.x - mu) * rstd * g.x + bt.x;
    r.y = (v.y - mu) * rstd * g.y + bt.y;
    r.z = (v.z - mu) * rstd * g.z + bt.z;
    r.w = (v.w - mu) * rstd * g.w + bt.w;
    *(float4*)&out[row * EMB + tid * 4] = r;
}

// ---------------------------------------------------------------------------
extern "C" void kernel_launch(void* const* d_in, const int* in_sizes, int n_in,
                              void* d_out, int out_size, void* d_ws, size_t ws_size,
                              hipStream_t stream) {
    const float* query = (const float*)d_in[0];
    const float* key_i = (const float*)d_in[1];
    const float* value = (const float*)d_in[2];
    const int*   mask  = (const int*)d_in[3];
    const float* Wq = (const float*)d_in[4];
    const float* bq = (const float*)d_in[5];
    const float* Wk = (const float*)d_in[6];
    const float* bk = (const float*)d_in[7];
    const float* Wv = (const float*)d_in[8];
    const float* bv = (const float*)d_in[9];
    const float* Wo = (const float*)d_in[10];
    const float* bo = (const float*)d_in[11];
    const float* gamma = (const float*)d_in[12];
    const float* beta  = (const float*)d_in[13];

    float* ws = (float*)d_ws;
    const size_t SZ = (size_t)NB * T_SEQ * EMB;
    float* qb    = ws;
    float* kb    = ws + SZ;
    float* vb    = ws + 2 * SZ;
    float* attnb = ws + 3 * SZ;
    float* projb = qb;

    const int M = NB * T_SEQ;
    dim3 gg(EMB / 128, M / 128);
    dim3 blk(256);

    gemm_bias<<<gg, blk, 0, stream>>>(query, Wq, bq, qb, M, EMB, EMB, 1);
    gemm_bias<<<gg, blk, 0, stream>>>(key_i, Wk, bk, kb, M, EMB, EMB, 1);
    gemm_bias<<<gg, blk, 0, stream>>>(value, Wv, bv, vb, M, EMB, EMB, 1);

    flash_attn_mfma<<<dim3(T_SEQ / BQ, NH, NB), blk, 0, stream>>>(qb, kb, vb, mask, attnb);

    gemm_bias<<<gg, blk, 0, stream>>>(attnb, Wo, bo, projb, M, EMB, EMB, 0);

    layernorm_k<<<dim3(M), blk, 0, stream>>>(projb, gamma, beta, (float*)d_out);
}

// Round 3
// 292.948 us; speedup vs baseline: 7.0989x; 3.5943x over previous
//
#include <hip/hip_runtime.h>
#include <cmath>

#define T_SEQ 1024
#define EMB   1024
#define NH    16
#define HD    64
#define NB    4
#define BQ    64
#define BK    64

using frag8   = __attribute__((ext_vector_type(8))) short;
using f32x4   = __attribute__((ext_vector_type(4))) float;
using short4v = __attribute__((ext_vector_type(4))) short;
using short8v = __attribute__((ext_vector_type(8))) short;

__device__ inline short f2bf(float f) {
    union { float f; unsigned u; } x; x.f = f;
    unsigned r = (x.u + 0x7FFFu + ((x.u >> 16) & 1u)) >> 16;
    return (short)r;
}

__device__ inline void glds16(const short* g, short* l) {
    __builtin_amdgcn_global_load_lds(
        (const __attribute__((address_space(1))) void*)g,
        (__attribute__((address_space(3))) void*)l, 16, 0, 0);
}

// ---------------------------------------------------------------------------
// fp32 -> bf16 converts (inputs + weights), one kernel, y = tensor index.
// ---------------------------------------------------------------------------
struct ConvArgs { const float* src[7]; short* dst[7]; int n8[7]; };

__global__ __launch_bounds__(256) void convert_bf16(ConvArgs a) {
    const int y = blockIdx.y;
    const int t = blockIdx.x * 256 + threadIdx.x;
    if (t >= a.n8[y]) return;
    const float4* s = (const float4*)a.src[y];
    const float4 v0 = s[t * 2], v1 = s[t * 2 + 1];
    short8v o;
    o[0] = f2bf(v0.x); o[1] = f2bf(v0.y); o[2] = f2bf(v0.z); o[3] = f2bf(v0.w);
    o[4] = f2bf(v1.x); o[5] = f2bf(v1.y); o[6] = f2bf(v1.z); o[7] = f2bf(v1.w);
    *(short8v*)&a.dst[y][t * 8] = o;
}

// ---------------------------------------------------------------------------
// bf16 MFMA GEMM core (m97 structure): C = A(MxK) @ W(NxK)^T + bias
// 128x128 tile, BK=32, 256 thr (4 waves, 2x2), 64x64 per wave.
// As/Bs row-major [128][32] shorts, staged via global_load_lds width=16.
// ---------------------------------------------------------------------------
struct GemmB { const short* A; const short* W; const float* bias; short* out; };
struct QkvArgs { GemmB g[3]; };

template <int SPLIT_HEADS>
__device__ inline void gemm_core(const short* __restrict__ A,
                                 const short* __restrict__ W,
                                 const float* __restrict__ bias,
                                 short* __restrict__ outS,
                                 float* __restrict__ outF)
{
    __shared__ short As[128 * 32];
    __shared__ short Bs[128 * 32];

    const int tid  = threadIdx.x;
    const int wave = tid >> 6;
    const int lane = tid & 63;
    const int quad = lane >> 4;
    const int lm   = lane & 15;
    const int wr   = wave >> 1;     // wave row (0..1)
    const int wc   = wave & 1;      // wave col (0..1)

    const int m0 = blockIdx.y * 128;
    const int n0 = blockIdx.x * 128;
    const int K  = EMB;

    // staging addresses: G = wave*64+lane (+256); r=G>>2, g=G&3
    const int G0 = wave * 64 + lane, G1 = G0 + 256;
    const short* aSrc0 = A + (size_t)(m0 + (G0 >> 2)) * K + (G0 & 3) * 8;
    const short* aSrc1 = A + (size_t)(m0 + (G1 >> 2)) * K + (G1 & 3) * 8;
    const short* bSrc0 = W + (size_t)(n0 + (G0 >> 2)) * K + (G0 & 3) * 8;
    const short* bSrc1 = W + (size_t)(n0 + (G1 >> 2)) * K + (G1 & 3) * 8;
    short* aDst0 = As + wave * 512;            // wave-uniform LDS bases
    short* aDst1 = As + 2048 + wave * 512;
    short* bDst0 = Bs + wave * 512;
    short* bDst1 = Bs + 2048 + wave * 512;

    f32x4 acc[4][4];
#pragma unroll
    for (int i = 0; i < 4; ++i)
#pragma unroll
        for (int j = 0; j < 4; ++j) acc[i][j] = (f32x4){0.f, 0.f, 0.f, 0.f};

    for (int kk = 0; kk < K; kk += 32) {
        __syncthreads();
        glds16(aSrc0 + kk, aDst0);
        glds16(aSrc1 + kk, aDst1);
        glds16(bSrc0 + kk, bDst0);
        glds16(bSrc1 + kk, bDst1);
        __syncthreads();

        frag8 aF[4], bF[4];
#pragma unroll
        for (int i = 0; i < 4; ++i)
            aF[i] = *(const frag8*)&As[(wr * 64 + i * 16 + lm) * 32 + quad * 8];
#pragma unroll
        for (int j = 0; j < 4; ++j)
            bF[j] = *(const frag8*)&Bs[(wc * 64 + j * 16 + lm) * 32 + quad * 8];
#pragma unroll
        for (int i = 0; i < 4; ++i)
#pragma unroll
            for (int j = 0; j < 4; ++j)
                acc[i][j] = __builtin_amdgcn_mfma_f32_16x16x32_bf16(
                    aF[i], bF[j], acc[i][j], 0, 0, 0);
    }

    // epilogue: C row = quad*4+rr, col = lm within each 16x16 tile
#pragma unroll
    for (int i = 0; i < 4; ++i)
#pragma unroll
        for (int j = 0; j < 4; ++j) {
            const int n = n0 + wc * 64 + j * 16 + lm;
            const float bv = bias[n];
#pragma unroll
            for (int rr = 0; rr < 4; ++rr) {
                const int m = m0 + wr * 64 + i * 16 + quad * 4 + rr;
                const float val = acc[i][j][rr] + bv;
                if (SPLIT_HEADS) {
                    const int bb = m >> 10, t = m & 1023;
                    const int h = n >> 6, d = n & 63;
                    outS[(((size_t)bb * NH + h) * T_SEQ + t) * HD + d] = f2bf(val);
                } else {
                    outF[(size_t)m * EMB + n] = val;
                }
            }
        }
}

__global__ __launch_bounds__(256) void gemm_qkv(QkvArgs args) {
    const GemmB g = args.g[blockIdx.z];
    gemm_core<1>(g.A, g.W, g.bias, g.out, nullptr);
}

__global__ __launch_bounds__(256) void gemm_wo(const short* __restrict__ A,
                                               const short* __restrict__ W,
                                               const float* __restrict__ bias,
                                               float* __restrict__ out) {
    gemm_core<0>(A, W, bias, nullptr, out);
}

// ---------------------------------------------------------------------------
// MFMA bf16 flash attention, bf16 Q/K/V in (B,H,T,D), bf16 out (B,T,E).
// ---------------------------------------------------------------------------
__global__ __launch_bounds__(256) void flash_attn_mfma(
    const short* __restrict__ q, const short* __restrict__ k,
    const short* __restrict__ v, const int* __restrict__ mask,
    short* __restrict__ out)
{
    __shared__ short Ks[64][72];
    __shared__ short Vt[64][64];
    __shared__ short Mh[64][72];
    __shared__ short Pl[4][16][72];

    const int tid  = threadIdx.x;
    const int wave = tid >> 6;
    const int lane = tid & 63;
    const int quad = lane >> 4;
    const int lm   = lane & 15;

    const int b  = blockIdx.z, h = blockIdx.y;
    const int q0 = blockIdx.x * BQ;

    const short* qrow = q + (((size_t)b * NH + h) * T_SEQ + q0 + wave * 16 + lm) * HD;
    const frag8 qf0 = *(const frag8*)&qrow[quad * 8];
    const frag8 qf1 = *(const frag8*)&qrow[32 + quad * 8];

    f32x4 of[4];
#pragma unroll
    for (int dc = 0; dc < 4; ++dc) of[dc] = (f32x4){0.f, 0.f, 0.f, 0.f};
    float mrun[4], lrun[4];
#pragma unroll
    for (int r = 0; r < 4; ++r) { mrun[r] = -INFINITY; lrun[r] = 0.f; }

    const short* kb0 = k + (((size_t)b * NH + h) * T_SEQ) * HD;
    const short* vb0 = v + (((size_t)b * NH + h) * T_SEQ) * HD;
    const int*   mb0 = mask + ((size_t)b * T_SEQ + q0) * T_SEQ;

    for (int kt = 0; kt < T_SEQ / BK; ++kt) {
        __syncthreads();
        // K tile (64x64 bf16)
        {
            const int r = tid >> 2, sg = (tid & 3) * 16;
            const short* src = kb0 + (size_t)(kt * 64 + r) * HD + sg;
            *(short8v*)&Ks[r][sg]     = *(const short8v*)&src[0];
            *(short8v*)&Ks[r][sg + 8] = *(const short8v*)&src[8];
        }
        // mask tile -> 0/1 shorts
        {
            const int r = tid >> 2, sg = (tid & 3) * 16;
            const int* src = mb0 + (size_t)r * T_SEQ + kt * 64 + sg;
            short tmp[16];
#pragma unroll
            for (int u = 0; u < 4; ++u) {
                int4 mi = ((const int4*)src)[u];
                tmp[u * 4 + 0] = (short)mi.x; tmp[u * 4 + 1] = (short)mi.y;
                tmp[u * 4 + 2] = (short)mi.z; tmp[u * 4 + 3] = (short)mi.w;
            }
            *(short8v*)&Mh[r][sg]     = *(short8v*)&tmp[0];
            *(short8v*)&Mh[r][sg + 8] = *(short8v*)&tmp[8];
        }
        // V transposed + xor-swizzled
        {
            const int d0 = (tid & 15) * 4, k0 = (tid >> 4) * 4;
            short4v rv[4];
#pragma unroll
            for (int r = 0; r < 4; ++r)
                rv[r] = *(const short4v*)(vb0 + (size_t)(kt * 64 + k0 + r) * HD + d0);
#pragma unroll
            for (int dd = 0; dd < 4; ++dd) {
                const int d = d0 + dd;
                short4v pk;
                pk[0] = rv[0][dd]; pk[1] = rv[1][dd];
                pk[2] = rv[2][dd]; pk[3] = rv[3][dd];
                const int col = k0 ^ (((d >> 1) & 7) << 3);
                *(short4v*)&Vt[d][col] = pk;
            }
        }
        __syncthreads();

        // S = Q K^T
        f32x4 s[4];
#pragma unroll
        for (int kc = 0; kc < 4; ++kc) {
            frag8 kf0 = *(const frag8*)&Ks[kc * 16 + lm][quad * 8];
            frag8 kf1 = *(const frag8*)&Ks[kc * 16 + lm][32 + quad * 8];
            f32x4 a = (f32x4){0.f, 0.f, 0.f, 0.f};
            a = __builtin_amdgcn_mfma_f32_16x16x32_bf16(qf0, kf0, a, 0, 0, 0);
            a = __builtin_amdgcn_mfma_f32_16x16x32_bf16(qf1, kf1, a, 0, 0, 0);
            s[kc] = a;
        }

        float tmax[4] = { -INFINITY, -INFINITY, -INFINITY, -INFINITY };
#pragma unroll
        for (int kc = 0; kc < 4; ++kc)
#pragma unroll
            for (int r = 0; r < 4; ++r) {
                float sv = s[kc][r] * 0.125f;
                sv = (Mh[wave * 16 + quad * 4 + r][kc * 16 + lm] != 0) ? sv : -1.0e9f;
                s[kc][r] = sv;
                tmax[r] = fmaxf(tmax[r], sv);
            }
#pragma unroll
        for (int r = 0; r < 4; ++r) {
            tmax[r] = fmaxf(tmax[r], __shfl_xor(tmax[r], 1));
            tmax[r] = fmaxf(tmax[r], __shfl_xor(tmax[r], 2));
            tmax[r] = fmaxf(tmax[r], __shfl_xor(tmax[r], 4));
            tmax[r] = fmaxf(tmax[r], __shfl_xor(tmax[r], 8));
        }

        float corr[4], rsum[4];
#pragma unroll
        for (int r = 0; r < 4; ++r) {
            const float mnew = fmaxf(mrun[r], tmax[r]);
            corr[r] = __expf(mrun[r] - mnew);
            mrun[r] = mnew;
            rsum[r] = 0.f;
        }
#pragma unroll
        for (int kc = 0; kc < 4; ++kc)
#pragma unroll
            for (int r = 0; r < 4; ++r) {
                const float p = __expf(s[kc][r] - mrun[r]);
                s[kc][r] = p;
                rsum[r] += p;
            }
#pragma unroll
        for (int r = 0; r < 4; ++r) {
            rsum[r] += __shfl_xor(rsum[r], 1);
            rsum[r] += __shfl_xor(rsum[r], 2);
            rsum[r] += __shfl_xor(rsum[r], 4);
            rsum[r] += __shfl_xor(rsum[r], 8);
            lrun[r] = lrun[r] * corr[r] + rsum[r];
        }
#pragma unroll
        for (int dc = 0; dc < 4; ++dc)
#pragma unroll
            for (int r = 0; r < 4; ++r) of[dc][r] *= corr[r];

        // P -> LDS (C -> A layout)
#pragma unroll
        for (int kc = 0; kc < 4; ++kc)
#pragma unroll
            for (int r = 0; r < 4; ++r)
                Pl[wave][quad * 4 + r][kc * 16 + lm] = f2bf(s[kc][r]);

        frag8 pf0 = *(const frag8*)&Pl[wave][lm][quad * 8];
        frag8 pf1 = *(const frag8*)&Pl[wave][lm][32 + quad * 8];
#pragma unroll
        for (int dc = 0; dc < 4; ++dc) {
            const int d = dc * 16 + lm;
            const int swz = ((d >> 1) & 7) << 3;
            frag8 vf0 = *(const frag8*)&Vt[d][(quad * 8) ^ swz];
            frag8 vf1 = *(const frag8*)&Vt[d][(32 + quad * 8) ^ swz];
            of[dc] = __builtin_amdgcn_mfma_f32_16x16x32_bf16(pf0, vf0, of[dc], 0, 0, 0);
            of[dc] = __builtin_amdgcn_mfma_f32_16x16x32_bf16(pf1, vf1, of[dc], 0, 0, 0);
        }
    }

    float inv[4];
#pragma unroll
    for (int r = 0; r < 4; ++r) inv[r] = 1.0f / lrun[r];
    short* ob = out + ((size_t)b * T_SEQ + q0 + wave * 16) * EMB + h * HD;
#pragma unroll
    for (int dc = 0; dc < 4; ++dc)
#pragma unroll
        for (int r = 0; r < 4; ++r)
            ob[(size_t)(quad * 4 + r) * EMB + dc * 16 + lm] = f2bf(of[dc][r] * inv[r]);
}

// ---------------------------------------------------------------------------
// LayerNorm over last dim (1024). One block (256 thr) per row. fp32 in/out.
// ---------------------------------------------------------------------------
__global__ __launch_bounds__(256) void layernorm_k(
    const float* __restrict__ x, const float* __restrict__ gamma,
    const float* __restrict__ beta, float* __restrict__ out)
{
    __shared__ float ws1[4], ws2[4];
    const int tid = threadIdx.x;
    const size_t row = blockIdx.x;

    const float4 v = *(const float4*)&x[row * EMB + tid * 4];
    float s  = v.x + v.y + v.z + v.w;
    float ss = v.x * v.x + v.y * v.y + v.z * v.z + v.w * v.w;
#pragma unroll
    for (int off = 32; off > 0; off >>= 1) {
        s  += __shfl_down(s, off);
        ss += __shfl_down(ss, off);
    }
    if ((tid & 63) == 0) { ws1[tid >> 6] = s; ws2[tid >> 6] = ss; }
    __syncthreads();
    if (tid == 0) {
        const float a = ws1[0] + ws1[1] + ws1[2] + ws1[3];
        const float bsum = ws2[0] + ws2[1] + ws2[2] + ws2[3];
        const float mu = a * (1.0f / EMB);
        const float var = bsum * (1.0f / EMB) - mu * mu;
        ws1[0] = mu;
        ws2[0] = rsqrtf(var + 1e-5f);
    }
    __syncthreads();
    const float mu = ws1[0], rstd = ws2[0];

    const float4 g = *(const float4*)&gamma[tid * 4];
    const float4 bt = *(const float4*)&beta[tid * 4];
    float4 r;
    r.x = (v.x - mu) * rstd * g.x + bt.x;
    r.y = (v.y - mu) * rstd * g.y + bt.y;
    r.z = (v.z - mu) * rstd * g.z + bt.z;
    r.w = (v.w - mu) * rstd * g.w + bt.w;
    *(float4*)&out[row * EMB + tid * 4] = r;
}

// ---------------------------------------------------------------------------
extern "C" void kernel_launch(void* const* d_in, const int* in_sizes, int n_in,
                              void* d_out, int out_size, void* d_ws, size_t ws_size,
                              hipStream_t stream) {
    const float* query = (const float*)d_in[0];
    const float* key_i = (const float*)d_in[1];
    const float* value = (const float*)d_in[2];
    const int*   mask  = (const int*)d_in[3];
    const float* Wq = (const float*)d_in[4];
    const float* bq = (const float*)d_in[5];
    const float* Wk = (const float*)d_in[6];
    const float* bk = (const float*)d_in[7];
    const float* Wv = (const float*)d_in[8];
    const float* bv = (const float*)d_in[9];
    const float* Wo = (const float*)d_in[10];
    const float* bo = (const float*)d_in[11];
    const float* gamma = (const float*)d_in[12];
    const float* beta  = (const float*)d_in[13];

    const size_t SZ = (size_t)NB * T_SEQ * EMB;   // 4M elements
    const size_t WZ = (size_t)EMB * EMB;          // 1M elements
    short* sws = (short*)d_ws;
    short* q_bf  = sws;               // dead after gemm_qkv
    short* k_bf  = sws + SZ;          // dead after gemm_qkv
    short* v_bf  = sws + 2 * SZ;      // dead after gemm_qkv
    short* w_bf  = sws + 3 * SZ;      // Wq,Wk,Wv,Wo bf16 (4 x 1M)
    short* qh    = sws + 4 * SZ;      // split-head Q bf16
    short* kh    = sws + 5 * SZ;
    short* vh    = sws + 6 * SZ;
    short* attnb = sws + 7 * SZ;      // attention out bf16 (B,T,E)
    float* projb = (float*)d_ws;      // fp32, overlays q_bf+k_bf (dead)

    // 1. converts
    ConvArgs ca;
    ca.src[0] = query; ca.dst[0] = q_bf;          ca.n8[0] = (int)(SZ / 8);
    ca.src[1] = key_i; ca.dst[1] = k_bf;          ca.n8[1] = (int)(SZ / 8);
    ca.src[2] = value; ca.dst[2] = v_bf;          ca.n8[2] = (int)(SZ / 8);
    ca.src[3] = Wq;    ca.dst[3] = w_bf;          ca.n8[3] = (int)(WZ / 8);
    ca.src[4] = Wk;    ca.dst[4] = w_bf + WZ;     ca.n8[4] = (int)(WZ / 8);
    ca.src[5] = Wv;    ca.dst[5] = w_bf + 2 * WZ; ca.n8[5] = (int)(WZ / 8);
    ca.src[6] = Wo;    ca.dst[6] = w_bf + 3 * WZ; ca.n8[6] = (int)(WZ / 8);
    convert_bf16<<<dim3((SZ / 8 + 255) / 256, 7), 256, 0, stream>>>(ca);

    // 2. QKV projections (batched, bf16 MFMA, split-head bf16 out)
    QkvArgs qa;
    qa.g[0] = { q_bf, w_bf,          bq, qh };
    qa.g[1] = { k_bf, w_bf + WZ,     bk, kh };
    qa.g[2] = { v_bf, w_bf + 2 * WZ, bv, vh };
    gemm_qkv<<<dim3(EMB / 128, NB * T_SEQ / 128, 3), 256, 0, stream>>>(qa);

    // 3. flash attention
    flash_attn_mfma<<<dim3(T_SEQ / BQ, NH, NB), 256, 0, stream>>>(qh, kh, vh, mask, attnb);

    // 4. output projection (bf16 MFMA, fp32 out)
    gemm_wo<<<dim3(EMB / 128, NB * T_SEQ / 128), 256, 0, stream>>>(
        attnb, w_bf + 3 * WZ, bo, projb);

    // 5. layernorm
    layernorm_k<<<dim3(NB * T_SEQ), 256, 0, stream>>>(projb, gamma, beta, (float*)d_out);
}